// Round 7
// baseline (160.735 us; speedup 1.0000x reference)
//
#include <hip/hip_runtime.h>

#define B_ 4
#define L_ 2048
#define E_ 512
#define H_ 8
#define NROW (B_*L_)        // 8192 flat rows
#define SZ (NROW*E_)        // 4194304
#define NH (B_*H_)          // 32 batch-heads

typedef unsigned short u16;
typedef unsigned int u32;
typedef __attribute__((ext_vector_type(8))) __bf16 bf16x8;
typedef __attribute__((ext_vector_type(8))) u16 u16x8;
typedef __attribute__((ext_vector_type(4))) float f32x4;

__device__ __forceinline__ u16 f2bf(float f) {
  union { float f; u32 u; } v; v.f = f;
  u32 r = v.u + 0x7FFFu + ((v.u >> 16) & 1u);   // RNE
  return (u16)(r >> 16);
}
__device__ __forceinline__ float bf2f(u16 s) {
  union { u32 u; float f; } v; v.u = ((u32)s) << 16;
  return v.f;
}
// async global->LDS, 16B per lane. lds dest = wave-uniform base + lane*16.
__device__ __forceinline__ void async16(const u16* g, u16* l) {
  __builtin_amdgcn_global_load_lds(
      (const __attribute__((address_space(1))) u32*)g,
      (__attribute__((address_space(3))) u32*)l, 16, 0, 0);
}

// ---------- fused fp32->bf16 converts ----------
// blocks [0,2048): X ; [2048,2560): 4 weights (128 blocks each)
__global__ __launch_bounds__(256) void cvt_all(const float* __restrict__ X,
    const float* __restrict__ W0, const float* __restrict__ W1,
    const float* __restrict__ W2, const float* __restrict__ W3,
    u16* __restrict__ Y, u16* __restrict__ Y0, u16* __restrict__ Y1,
    u16* __restrict__ Y2, u16* __restrict__ Y3) {
  const int bid = blockIdx.x;
  const float* src;
  u16* dst;
  int off;
  if (bid < 2048) { src = X; dst = Y; off = bid * 2048; }
  else {
    const int t = bid - 2048, s = t >> 7, r = t & 127;
    src = (s == 0) ? W0 : (s == 1) ? W1 : (s == 2) ? W2 : W3;
    dst = (s == 0) ? Y0 : (s == 1) ? Y1 : (s == 2) ? Y2 : Y3;
    off = r * 2048;
  }
  const int i0 = off + threadIdx.x * 8;
  f32x4 a = *(const f32x4*)(src + i0);
  f32x4 b = *(const f32x4*)(src + i0 + 4);
  u16x8 o;
#pragma unroll
  for (int j = 0; j < 4; ++j) { o[j] = f2bf(a[j]); o[4 + j] = f2bf(b[j]); }
  *(u16x8*)(dst + i0) = o;
}

// ---------- z-fused QKV MFMA GEMM: 128x64 tile, BK=32, grid (64,8) ----------
// Each block computes Q,K,V for one (m,n) tile: X staged ONCE per k-iter,
// 3 W tiles, 24 MFMA per barrier pair. 4 waves stacked along M
// (wave = 32 rows x 64 cols = one head slice -> softmax stays wave-local).
__global__ __launch_bounds__(256) void qkv_gemm(const u16* __restrict__ X,
    const u16* __restrict__ Wq, const u16* __restrict__ Wk, const u16* __restrict__ Wv,
    const float* __restrict__ bq, const float* __restrict__ bk, const float* __restrict__ bv,
    u16* __restrict__ Qo, u16* __restrict__ Ko, u16* __restrict__ Vo) {
  __shared__ __align__(16) union {
    struct { u16 a[128 * 32]; u16 b[3][64 * 32]; } st;  // 8 + 12 = 20 KB
    u16 ep[4][16 * 72];                                 // per-wave epilogue stage
  } sh;
  const u16* Ws[3] = {Wq, Wk, Wv};
  const float* bs[3] = {bq, bk, bv};
  u16* Cs[3] = {Qo, Ko, Vo};
  const int tid = threadIdx.x;
  const int w = tid >> 6, lane = tid & 63;
  const int bm = blockIdx.x * 128, bn = blockIdx.y * 64;
  const int fr = lane & 15, quad = lane >> 4;
  const int c0 = tid, c1 = tid + 256;      // staging chunk ids (row = c>>2, k8 = c&3)
  f32x4 acc[3][2][4] = {};
  for (int k0 = 0; k0 < E_; k0 += 32) {
    __syncthreads();
    async16(X + (size_t)(bm + (c0 >> 2)) * E_ + k0 + (c0 & 3) * 8, sh.st.a + c0 * 8);
    async16(X + (size_t)(bm + (c1 >> 2)) * E_ + k0 + (c1 & 3) * 8, sh.st.a + c1 * 8);
#pragma unroll
    for (int zz = 0; zz < 3; ++zz)
      async16(Ws[zz] + (size_t)(bn + (c0 >> 2)) * E_ + k0 + (c0 & 3) * 8,
              sh.st.b[zz] + c0 * 8);
    __syncthreads();
    bf16x8 af[2];
#pragma unroll
    for (int mt = 0; mt < 2; ++mt)
      af[mt] = *(const bf16x8*)(sh.st.a + (w * 32 + mt * 16 + fr) * 32 + quad * 8);
#pragma unroll
    for (int zz = 0; zz < 3; ++zz) {
      bf16x8 bf[4];
#pragma unroll
      for (int nt = 0; nt < 4; ++nt)
        bf[nt] = *(const bf16x8*)(sh.st.b[zz] + (nt * 16 + fr) * 32 + quad * 8);
#pragma unroll
      for (int mt = 0; mt < 2; ++mt)
#pragma unroll
        for (int nt = 0; nt < 4; ++nt)
          acc[zz][mt][nt] = __builtin_amdgcn_mfma_f32_16x16x32_bf16(af[mt], bf[nt],
                                                                    acc[zz][mt][nt], 0, 0, 0);
    }
  }
  __syncthreads();   // all fragment reads done before LDS reuse
  u16* ep = sh.ep[w];
#pragma unroll
  for (int zz = 0; zz < 3; ++zz) {
    const float* bias = bs[zz];
    u16* C = Cs[zz];
#pragma unroll
    for (int mt = 0; mt < 2; ++mt) {
      if (zz < 2) {
#pragma unroll
        for (int r = 0; r < 4; ++r) {
          float v[4];
#pragma unroll
          for (int nt = 0; nt < 4; ++nt)
            v[nt] = acc[zz][mt][nt][r] + bias[bn + nt * 16 + fr];
          float mx = fmaxf(fmaxf(v[0], v[1]), fmaxf(v[2], v[3]));
#pragma unroll
          for (int off = 1; off < 16; off <<= 1) mx = fmaxf(mx, __shfl_xor(mx, off, 64));
          float e[4], ssum = 0.f;
#pragma unroll
          for (int nt = 0; nt < 4; ++nt) { e[nt] = __expf(v[nt] - mx); ssum += e[nt]; }
#pragma unroll
          for (int off = 1; off < 16; off <<= 1) ssum += __shfl_xor(ssum, off, 64);
          const float inv = 1.f / ssum;
#pragma unroll
          for (int nt = 0; nt < 4; ++nt)
            ep[(quad * 4 + r) * 72 + nt * 16 + fr] = f2bf(e[nt] * inv);
        }
      } else {
#pragma unroll
        for (int r = 0; r < 4; ++r)
#pragma unroll
          for (int nt = 0; nt < 4; ++nt)
            ep[(quad * 4 + r) * 72 + nt * 16 + fr] =
                f2bf(acc[zz][mt][nt][r] + bias[bn + nt * 16 + fr]);
      }
      // coalesced store: 16 rows x 64 cols bf16
#pragma unroll
      for (int pass = 0; pass < 2; ++pass) {
        const int row = pass * 8 + (lane >> 3), ch = lane & 7;
        u16x8 val = *(const u16x8*)(ep + row * 72 + ch * 8);
        *(u16x8*)(C + (size_t)(bm + w * 32 + mt * 16 + row) * E_ + bn + ch * 8) = val;
      }
    }
  }
}

// ---------- out-projection GEMM: 128x64 tile, fp32 out + bias, grid (64,8) ----------
__global__ __launch_bounds__(256) void gemm_out(const u16* __restrict__ X,
    const u16* __restrict__ W, const float* __restrict__ bias, float* __restrict__ C) {
  __shared__ __align__(16) union {
    struct { u16 a[128 * 32]; u16 b[64 * 32]; } st;  // 12 KB staging
    float ep[4][16 * 68];                            // per-wave fp32 stage (stride 68)
  } sh;
  const int tid = threadIdx.x;
  const int w = tid >> 6, lane = tid & 63;
  const int bm = blockIdx.x * 128, bn = blockIdx.y * 64;
  const int fr = lane & 15, quad = lane >> 4;
  const int c0 = tid, c1 = tid + 256;
  f32x4 acc[2][4] = {};
  for (int k0 = 0; k0 < E_; k0 += 32) {
    __syncthreads();
    async16(X + (size_t)(bm + (c0 >> 2)) * E_ + k0 + (c0 & 3) * 8, sh.st.a + c0 * 8);
    async16(X + (size_t)(bm + (c1 >> 2)) * E_ + k0 + (c1 & 3) * 8, sh.st.a + c1 * 8);
    async16(W + (size_t)(bn + (c0 >> 2)) * E_ + k0 + (c0 & 3) * 8, sh.st.b + c0 * 8);
    __syncthreads();
    bf16x8 af[2], bf[4];
#pragma unroll
    for (int mt = 0; mt < 2; ++mt)
      af[mt] = *(const bf16x8*)(sh.st.a + (w * 32 + mt * 16 + fr) * 32 + quad * 8);
#pragma unroll
    for (int nt = 0; nt < 4; ++nt)
      bf[nt] = *(const bf16x8*)(sh.st.b + (nt * 16 + fr) * 32 + quad * 8);
#pragma unroll
    for (int mt = 0; mt < 2; ++mt)
#pragma unroll
      for (int nt = 0; nt < 4; ++nt)
        acc[mt][nt] = __builtin_amdgcn_mfma_f32_16x16x32_bf16(af[mt], bf[nt], acc[mt][nt], 0, 0, 0);
  }
  __syncthreads();
  float* ep = sh.ep[w];
#pragma unroll
  for (int mt = 0; mt < 2; ++mt) {
#pragma unroll
    for (int r = 0; r < 4; ++r)
#pragma unroll
      for (int nt = 0; nt < 4; ++nt)
        ep[(quad * 4 + r) * 68 + nt * 16 + fr] = acc[mt][nt][r] + bias[bn + nt * 16 + fr];
#pragma unroll
    for (int p = 0; p < 4; ++p) {
      const int id = p * 64 + lane;
      const int row = id >> 4, ch = id & 15;
      f32x4 val = *(const f32x4*)(ep + row * 68 + ch * 4);
      *(f32x4*)(C + (size_t)(bm + w * 32 + mt * 16 + row) * E_ + bn + ch * 4) = val;
    }
  }
}

// ---------- kv_reduce stage 1: grid (NH, 16), 128 rows/block, NO atomics ----------
// Part[(n*16+sy)*4096 + e*64 + d] = partial sum_l K[l][d]*V[l][e]  (Mt layout [e][d])
__global__ __launch_bounds__(256) void kv_part(const u16* __restrict__ K,
    const u16* __restrict__ V, float* __restrict__ Part,
    float* __restrict__ KPart, float* __restrict__ VPart) {
  const int n = blockIdx.x, b = n >> 3, h = n & 7;
  const int sy = blockIdx.y;
  const int tid = threadIdx.x;
  const int td = tid & 15, te = tid >> 4;
  __shared__ float sK[32][68], sV[32][68];   // +4 pad
  float acc[4][4] = {};
  float srow = 0.f;
  const int which = tid >> 7, sub = tid & 127;       // 128 threads per tensor
  const int lr = sub >> 2, ck = (sub & 3) * 16;      // row 0..31, col {0,16,32,48}
  const u16* src = which ? V : K;
  float* dstrow = which ? &sV[lr][ck] : &sK[lr][ck];
  const int l0beg = sy * 128;
  for (int l0 = l0beg; l0 < l0beg + 128; l0 += 32) {
    const u16* g = src + (size_t)((l0 + lr) * B_ + b) * E_ + h * 64 + ck;
    u16x8 d0 = *(const u16x8*)g;
    u16x8 d1 = *(const u16x8*)(g + 8);
    __syncthreads();                  // previous chunk fully consumed
    f32x4 f0, f1, f2, f3;
#pragma unroll
    for (int j = 0; j < 4; ++j) {
      f0[j] = bf2f(d0[j]); f1[j] = bf2f(d0[4 + j]);
      f2[j] = bf2f(d1[j]); f3[j] = bf2f(d1[4 + j]);
    }
    *(f32x4*)(dstrow) = f0; *(f32x4*)(dstrow + 4) = f1;
    *(f32x4*)(dstrow + 8) = f2; *(f32x4*)(dstrow + 12) = f3;
    __syncthreads();
#pragma unroll 8
    for (int p = 0; p < 32; ++p) {
      f32x4 kk = *(const f32x4*)&sK[p][td * 4];
      f32x4 vv = *(const f32x4*)&sV[p][te * 4];
#pragma unroll
      for (int i = 0; i < 4; ++i)
#pragma unroll
        for (int j = 0; j < 4; ++j)
          acc[i][j] = fmaf(kk[i], vv[j], acc[i][j]);
      if (tid < 64) srow += sK[p][tid];
      else if (tid < 128) srow += sV[p][tid - 64];
    }
  }
  float* Pp = Part + (size_t)(n * 16 + sy) * 4096;
#pragma unroll
  for (int j = 0; j < 4; ++j) {
    f32x4 v4 = {acc[0][j], acc[1][j], acc[2][j], acc[3][j]};
    *(f32x4*)(Pp + (te * 4 + j) * 64 + td * 4) = v4;
  }
  if (tid < 64) KPart[(n * 16 + sy) * 64 + tid] = srow;
  else if (tid < 128) VPart[(n * 16 + sy) * 64 + tid - 64] = srow;
}

// ---------- kv_reduce stage 2: sum 16 slice-partials ----------
// blocks [0,512): Mt (32*4096 outputs); [512,528): Ksum/Vsum (4096 outputs)
__global__ __launch_bounds__(256) void kv_merge(const float* __restrict__ Part,
    const float* __restrict__ KPart, const float* __restrict__ VPart,
    float* __restrict__ Mt, float* __restrict__ Ks, float* __restrict__ Vs) {
  const int bid = blockIdx.x, tid = threadIdx.x;
  if (bid < 512) {
    const int oi = bid * 256 + tid;            // 0..131071
    const int n = oi >> 12, j = oi & 4095;
    const float* p = Part + (size_t)n * 16 * 4096 + j;
    float s = 0.f;
#pragma unroll
    for (int sl = 0; sl < 16; ++sl) s += p[sl * 4096];
    Mt[oi] = s;
  } else {
    const int i = (bid - 512) * 256 + tid;     // 0..4095
    const int which = i >> 11, rem = i & 2047;
    const int n = rem >> 6, d = rem & 63;
    const float* p = (which ? VPart : KPart) + (n * 16) * 64 + d;
    float s = 0.f;
#pragma unroll
    for (int sl = 0; sl < 16; ++sl) s += p[sl * 64];
    if (which) Vs[n * 64 + d] = s; else Ks[n * 64 + d] = s;
  }
}

// ---------- apply: A = (2*Q@M + 62*Vsum) / den, den = 2*q.Ksum + 62*L ----------
// grid (NH, 16). Stages fp32 Mt -> bf16 sM in-kernel.
__global__ __launch_bounds__(256) void apply_mfma(const u16* __restrict__ Qbf,
    const float* __restrict__ Mt, const float* __restrict__ Ksum,
    const float* __restrict__ Vsum, u16* __restrict__ Abf) {
  __shared__ __align__(16) u16 sQ[128 * 64];
  __shared__ __align__(16) u16 sM[64 * 64];
  __shared__ float sKs[64], sVs[64], sDen[128];
  const int n = blockIdx.x, b = n >> 3, h = n & 7;
  const int l0 = blockIdx.y * 128;
  const int tid = threadIdx.x, w = tid >> 6, lane = tid & 63;
  const int fr = lane & 15, quad = lane >> 4;
#pragma unroll
  for (int j = 0; j < 4; ++j) {
    const int rloc = w * 32 + j * 8;
    const int row = rloc + (lane >> 3);
    const int k = (lane & 7) * 8;
    async16(Qbf + (size_t)((l0 + row) * B_ + b) * E_ + h * 64 + k, sQ + rloc * 64);
  }
  {  // Mt fp32 -> sM bf16
    const float* Mp = Mt + (size_t)n * 4096 + tid * 16;
    f32x4 m0 = *(const f32x4*)(Mp);
    f32x4 m1 = *(const f32x4*)(Mp + 4);
    f32x4 m2 = *(const f32x4*)(Mp + 8);
    f32x4 m3 = *(const f32x4*)(Mp + 12);
    u16x8 o0, o1;
#pragma unroll
    for (int j = 0; j < 4; ++j) {
      o0[j] = f2bf(m0[j]); o0[4 + j] = f2bf(m1[j]);
      o1[j] = f2bf(m2[j]); o1[4 + j] = f2bf(m3[j]);
    }
    *(u16x8*)(sM + tid * 16) = o0;
    *(u16x8*)(sM + tid * 16 + 8) = o1;
  }
  if (tid < 64) sKs[tid] = Ksum[n * 64 + tid];
  else if (tid < 128) sVs[tid - 64] = Vsum[n * 64 + tid - 64];
  __syncthreads();
  union { u16x8 u; bf16x8 bv; } aU[2][2];
  bf16x8 bF[4][2];
#pragma unroll
  for (int mt = 0; mt < 2; ++mt)
#pragma unroll
    for (int ks = 0; ks < 2; ++ks)
      aU[mt][ks].u = *(const u16x8*)(sQ + (w * 32 + mt * 16 + fr) * 64 + ks * 32 + quad * 8);
#pragma unroll
  for (int nt = 0; nt < 4; ++nt)
#pragma unroll
    for (int ks = 0; ks < 2; ++ks)
      bF[nt][ks] = *(const bf16x8*)(sM + (nt * 16 + fr) * 64 + ks * 32 + quad * 8);
  float pden[2] = {0.f, 0.f};
#pragma unroll
  for (int mt = 0; mt < 2; ++mt)
#pragma unroll
    for (int ks = 0; ks < 2; ++ks)
#pragma unroll
      for (int j = 0; j < 8; ++j)
        pden[mt] = fmaf(bf2f(aU[mt][ks].u[j]), sKs[ks * 32 + quad * 8 + j], pden[mt]);
#pragma unroll
  for (int mt = 0; mt < 2; ++mt) {
    pden[mt] += __shfl_xor(pden[mt], 16, 64);
    pden[mt] += __shfl_xor(pden[mt], 32, 64);
    if (quad == 0)
      sDen[w * 32 + mt * 16 + fr] = fmaxf(2.f * pden[mt] + 62.f * (float)L_, 1e-6f);
  }
  __syncthreads();
  f32x4 acc[2][4];
#pragma unroll
  for (int mt = 0; mt < 2; ++mt)
#pragma unroll
    for (int nt = 0; nt < 4; ++nt) {
      const float iv = 31.f * sVs[nt * 16 + fr];
      acc[mt][nt] = (f32x4){iv, iv, iv, iv};
#pragma unroll
      for (int ks = 0; ks < 2; ++ks)
        acc[mt][nt] = __builtin_amdgcn_mfma_f32_16x16x32_bf16(aU[mt][ks].bv, bF[nt][ks],
                                                              acc[mt][nt], 0, 0, 0);
    }
#pragma unroll
  for (int mt = 0; mt < 2; ++mt)
#pragma unroll
    for (int r = 0; r < 4; ++r) {
      const int rloc = w * 32 + mt * 16 + quad * 4 + r;
      const float invd = 2.f / sDen[rloc];
      const size_t orow = (size_t)((l0 + rloc) * B_ + b) * E_ + h * 64;
#pragma unroll
      for (int nt = 0; nt < 4; ++nt)
        Abf[orow + nt * 16 + fr] = f2bf(acc[mt][nt][r] * invd);
    }
}

extern "C" void kernel_launch(void* const* d_in, const int* in_sizes, int n_in,
                              void* d_out, int out_size, void* d_ws, size_t ws_size,
                              hipStream_t stream) {
  const float* query = (const float*)d_in[0];
  const float* Wq = (const float*)d_in[1];
  const float* bq = (const float*)d_in[2];
  const float* Wk = (const float*)d_in[3];
  const float* bk = (const float*)d_in[4];
  const float* Wv = (const float*)d_in[5];
  const float* bv = (const float*)d_in[6];
  const float* Wo = (const float*)d_in[7];
  const float* bo = (const float*)d_in[8];
  float* out = (float*)d_out;

  char* ws = (char*)d_ws;
  u16* Xbf  = (u16*)(ws);                        // 8 MB; dead after qkv_gemm
  u16* Qbf  = (u16*)(ws + 8388608);
  u16* Kbf  = (u16*)(ws + 16777216);
  u16* Vbf  = (u16*)(ws + 25165824);
  u16* Abf  = (u16*)(ws + 33554432);
  u16* Wqb  = (u16*)(ws + 41943040);             // 512 KB each
  u16* Wkb  = (u16*)(ws + 42467328);
  u16* Wvb  = (u16*)(ws + 42991616);
  u16* Wob  = (u16*)(ws + 43515904);
  float* Mt = (float*)(ws + 44040192);           // 512 KB (NH*4096 f32)
  float* Ks = (float*)(ws + 44564480);           // 8 KB
  float* Vs = (float*)(ws + 44572672);           // 8 KB
  float* KPart = (float*)(ws + 44580864);        // 128 KB (512*64 f32)
  float* VPart = (float*)(ws + 44711936);        // 128 KB
  float* Part  = (float*)Xbf;                    // alias: 512*4096 f32 = 8 MB exactly

  cvt_all<<<2560, 256, 0, stream>>>(query, Wq, Wk, Wv, Wo,
                                    Xbf, Wqb, Wkb, Wvb, Wob);
  qkv_gemm<<<dim3(NROW / 128, E_ / 64), 256, 0, stream>>>(
      Xbf, Wqb, Wkb, Wvb, bq, bk, bv, Qbf, Kbf, Vbf);
  kv_part<<<dim3(NH, 16), 256, 0, stream>>>(Kbf, Vbf, Part, KPart, VPart);
  kv_merge<<<528, 256, 0, stream>>>(Part, KPart, VPart, Mt, Ks, Vs);
  apply_mfma<<<dim3(NH, L_ / 128), 256, 0, stream>>>(Qbf, Mt, Ks, Vs, Abf);
  gemm_out<<<dim3(NROW / 128, E_ / 64), 256, 0, stream>>>(Abf, Wob, bo, out);
}

// Round 8
// 145.613 us; speedup vs baseline: 1.1039x; 1.1039x over previous
//
#include <hip/hip_runtime.h>

#define B_ 4
#define L_ 2048
#define E_ 512
#define H_ 8
#define NROW (B_*L_)        // 8192 flat rows
#define SZ (NROW*E_)        // 4194304
#define NH (B_*H_)          // 32 batch-heads

typedef unsigned short u16;
typedef unsigned int u32;
typedef __attribute__((ext_vector_type(8))) __bf16 bf16x8;
typedef __attribute__((ext_vector_type(8))) u16 u16x8;
typedef __attribute__((ext_vector_type(4))) float f32x4;

__device__ __forceinline__ u16 f2bf(float f) {
  union { float f; u32 u; } v; v.f = f;
  u32 r = v.u + 0x7FFFu + ((v.u >> 16) & 1u);   // RNE
  return (u16)(r >> 16);
}
__device__ __forceinline__ float bf2f(u16 s) {
  union { u32 u; float f; } v; v.u = ((u32)s) << 16;
  return v.f;
}
// async global->LDS, 16B per lane. lds dest = wave-uniform base + lane*16.
__device__ __forceinline__ void async16(const u16* g, u16* l) {
  __builtin_amdgcn_global_load_lds(
      (const __attribute__((address_space(1))) u32*)g,
      (__attribute__((address_space(3))) u32*)l, 16, 0, 0);
}

// ---------- fused fp32->bf16 converts ----------
// blocks [0,2048): X ; [2048,2560): 4 weights (128 blocks each)
__global__ __launch_bounds__(256) void cvt_all(const float* __restrict__ X,
    const float* __restrict__ W0, const float* __restrict__ W1,
    const float* __restrict__ W2, const float* __restrict__ W3,
    u16* __restrict__ Y, u16* __restrict__ Y0, u16* __restrict__ Y1,
    u16* __restrict__ Y2, u16* __restrict__ Y3) {
  const int bid = blockIdx.x;
  const float* src;
  u16* dst;
  int off;
  if (bid < 2048) { src = X; dst = Y; off = bid * 2048; }
  else {
    const int t = bid - 2048, s = t >> 7, r = t & 127;
    src = (s == 0) ? W0 : (s == 1) ? W1 : (s == 2) ? W2 : W3;
    dst = (s == 0) ? Y0 : (s == 1) ? Y1 : (s == 2) ? Y2 : Y3;
    off = r * 2048;
  }
  const int i0 = off + threadIdx.x * 8;
  f32x4 a = *(const f32x4*)(src + i0);
  f32x4 b = *(const f32x4*)(src + i0 + 4);
  u16x8 o;
#pragma unroll
  for (int j = 0; j < 4; ++j) { o[j] = f2bf(a[j]); o[4 + j] = f2bf(b[j]); }
  *(u16x8*)(dst + i0) = o;
}

// ---------- QKV MFMA GEMM: 128x64 tile, two BK=32 panels/barrier, grid (64,8,3) ----------
// 4 waves stacked along M (wave = 32 rows x 64 cols = one head slice).
// 16 MFMA per barrier pair (vs 8 in R6): halves the vmcnt(0)+barrier drains.
// z=0: Q (+softmax64), z=1: K (+softmax64), z=2: V (plain bf16)
__global__ __launch_bounds__(256) void qkv_gemm(const u16* __restrict__ X,
    const u16* __restrict__ Wq, const u16* __restrict__ Wk, const u16* __restrict__ Wv,
    const float* __restrict__ bq, const float* __restrict__ bk, const float* __restrict__ bv,
    u16* __restrict__ Qo, u16* __restrict__ Ko, u16* __restrict__ Vo) {
  __shared__ __align__(16) union {
    struct { u16 a[2][128 * 32]; u16 b[2][64 * 32]; } st;  // 16 + 8 = 24 KB
    u16 ep[4][16 * 72];                                    // per-wave epilogue stage
  } sh;
  const int z = blockIdx.z;
  const u16* W = (z == 0) ? Wq : (z == 1) ? Wk : Wv;
  const float* bias = (z == 0) ? bq : (z == 1) ? bk : bv;
  u16* C = (z == 0) ? Qo : (z == 1) ? Ko : Vo;
  const int tid = threadIdx.x;
  const int w = tid >> 6, lane = tid & 63;
  const int bm = blockIdx.x * 128, bn = blockIdx.y * 64;
  const int fr = lane & 15, quad = lane >> 4;
  const int c0 = tid, c1 = tid + 256;      // chunk ids within a panel (row=c>>2, k8=c&3)
  const int ar0 = c0 >> 2, ak0 = (c0 & 3) * 8;
  const int ar1 = c1 >> 2, ak1 = (c1 & 3) * 8;
  f32x4 acc[2][4] = {};
  for (int k0 = 0; k0 < E_; k0 += 64) {
    __syncthreads();
#pragma unroll
    for (int p = 0; p < 2; ++p) {
      const int kp = k0 + p * 32;
      async16(X + (size_t)(bm + ar0) * E_ + kp + ak0, sh.st.a[p] + c0 * 8);
      async16(X + (size_t)(bm + ar1) * E_ + kp + ak1, sh.st.a[p] + c1 * 8);
      async16(W + (size_t)(bn + ar0) * E_ + kp + ak0, sh.st.b[p] + c0 * 8);
    }
    __syncthreads();
#pragma unroll
    for (int p = 0; p < 2; ++p) {
      bf16x8 af[2], bf[4];
#pragma unroll
      for (int mt = 0; mt < 2; ++mt)
        af[mt] = *(const bf16x8*)(sh.st.a[p] + (w * 32 + mt * 16 + fr) * 32 + quad * 8);
#pragma unroll
      for (int nt = 0; nt < 4; ++nt)
        bf[nt] = *(const bf16x8*)(sh.st.b[p] + (nt * 16 + fr) * 32 + quad * 8);
#pragma unroll
      for (int mt = 0; mt < 2; ++mt)
#pragma unroll
        for (int nt = 0; nt < 4; ++nt)
          acc[mt][nt] = __builtin_amdgcn_mfma_f32_16x16x32_bf16(af[mt], bf[nt],
                                                                acc[mt][nt], 0, 0, 0);
    }
  }
  __syncthreads();   // all fragment reads done before LDS reuse
  u16* ep = sh.ep[w];
#pragma unroll
  for (int mt = 0; mt < 2; ++mt) {
    if (z < 2) {
#pragma unroll
      for (int r = 0; r < 4; ++r) {
        float v[4];
#pragma unroll
        for (int nt = 0; nt < 4; ++nt)
          v[nt] = acc[mt][nt][r] + bias[bn + nt * 16 + fr];
        float mx = fmaxf(fmaxf(v[0], v[1]), fmaxf(v[2], v[3]));
#pragma unroll
        for (int off = 1; off < 16; off <<= 1) mx = fmaxf(mx, __shfl_xor(mx, off, 64));
        float e[4], ssum = 0.f;
#pragma unroll
        for (int nt = 0; nt < 4; ++nt) { e[nt] = __expf(v[nt] - mx); ssum += e[nt]; }
#pragma unroll
        for (int off = 1; off < 16; off <<= 1) ssum += __shfl_xor(ssum, off, 64);
        const float inv = 1.f / ssum;
#pragma unroll
        for (int nt = 0; nt < 4; ++nt)
          ep[(quad * 4 + r) * 72 + nt * 16 + fr] = f2bf(e[nt] * inv);
      }
    } else {
#pragma unroll
      for (int r = 0; r < 4; ++r)
#pragma unroll
        for (int nt = 0; nt < 4; ++nt)
          ep[(quad * 4 + r) * 72 + nt * 16 + fr] = f2bf(acc[mt][nt][r] + bias[bn + nt * 16 + fr]);
    }
    // coalesced store: 16 rows x 64 cols bf16
#pragma unroll
    for (int pass = 0; pass < 2; ++pass) {
      const int row = pass * 8 + (lane >> 3), ch = lane & 7;
      u16x8 val = *(const u16x8*)(ep + row * 72 + ch * 8);
      *(u16x8*)(C + (size_t)(bm + w * 32 + mt * 16 + row) * E_ + bn + ch * 8) = val;
    }
  }
}

// ---------- out-projection GEMM: 128x64 tile, two BK=32 panels, fp32 out, grid (64,8) ----------
__global__ __launch_bounds__(256) void gemm_out(const u16* __restrict__ X,
    const u16* __restrict__ W, const float* __restrict__ bias, float* __restrict__ C) {
  __shared__ __align__(16) union {
    struct { u16 a[2][128 * 32]; u16 b[2][64 * 32]; } st;  // 24 KB
    float ep[4][16 * 68];                                  // per-wave fp32 stage
  } sh;
  const int tid = threadIdx.x;
  const int w = tid >> 6, lane = tid & 63;
  const int bm = blockIdx.x * 128, bn = blockIdx.y * 64;
  const int fr = lane & 15, quad = lane >> 4;
  const int c0 = tid, c1 = tid + 256;
  const int ar0 = c0 >> 2, ak0 = (c0 & 3) * 8;
  const int ar1 = c1 >> 2, ak1 = (c1 & 3) * 8;
  f32x4 acc[2][4] = {};
  for (int k0 = 0; k0 < E_; k0 += 64) {
    __syncthreads();
#pragma unroll
    for (int p = 0; p < 2; ++p) {
      const int kp = k0 + p * 32;
      async16(X + (size_t)(bm + ar0) * E_ + kp + ak0, sh.st.a[p] + c0 * 8);
      async16(X + (size_t)(bm + ar1) * E_ + kp + ak1, sh.st.a[p] + c1 * 8);
      async16(W + (size_t)(bn + ar0) * E_ + kp + ak0, sh.st.b[p] + c0 * 8);
    }
    __syncthreads();
#pragma unroll
    for (int p = 0; p < 2; ++p) {
      bf16x8 af[2], bf[4];
#pragma unroll
      for (int mt = 0; mt < 2; ++mt)
        af[mt] = *(const bf16x8*)(sh.st.a[p] + (w * 32 + mt * 16 + fr) * 32 + quad * 8);
#pragma unroll
      for (int nt = 0; nt < 4; ++nt)
        bf[nt] = *(const bf16x8*)(sh.st.b[p] + (nt * 16 + fr) * 32 + quad * 8);
#pragma unroll
      for (int mt = 0; mt < 2; ++mt)
#pragma unroll
        for (int nt = 0; nt < 4; ++nt)
          acc[mt][nt] = __builtin_amdgcn_mfma_f32_16x16x32_bf16(af[mt], bf[nt],
                                                                acc[mt][nt], 0, 0, 0);
    }
  }
  __syncthreads();
  float* ep = sh.ep[w];
#pragma unroll
  for (int mt = 0; mt < 2; ++mt) {
#pragma unroll
    for (int r = 0; r < 4; ++r)
#pragma unroll
      for (int nt = 0; nt < 4; ++nt)
        ep[(quad * 4 + r) * 68 + nt * 16 + fr] = acc[mt][nt][r] + bias[bn + nt * 16 + fr];
#pragma unroll
    for (int p = 0; p < 4; ++p) {
      const int id = p * 64 + lane;
      const int row = id >> 4, ch = id & 15;
      f32x4 val = *(const f32x4*)(ep + row * 68 + ch * 4);
      *(f32x4*)(C + (size_t)(bm + w * 32 + mt * 16 + row) * E_ + bn + ch * 4) = val;
    }
  }
}

// ---------- kv_reduce stage 1: grid (NH, 16), 128 rows/block, NO atomics ----------
// Part[(n*16+sy)*4096 + e*64 + d] = partial sum_l K[l][d]*V[l][e]  (Mt layout [e][d])
__global__ __launch_bounds__(256) void kv_part(const u16* __restrict__ K,
    const u16* __restrict__ V, float* __restrict__ Part,
    float* __restrict__ KPart, float* __restrict__ VPart) {
  const int n = blockIdx.x, b = n >> 3, h = n & 7;
  const int sy = blockIdx.y;
  const int tid = threadIdx.x;
  const int td = tid & 15, te = tid >> 4;
  __shared__ float sK[32][68], sV[32][68];   // +4 pad
  float acc[4][4] = {};
  float srow = 0.f;
  const int which = tid >> 7, sub = tid & 127;       // 128 threads per tensor
  const int lr = sub >> 2, ck = (sub & 3) * 16;      // row 0..31, col {0,16,32,48}
  const u16* src = which ? V : K;
  float* dstrow = which ? &sV[lr][ck] : &sK[lr][ck];
  const int l0beg = sy * 128;
  for (int l0 = l0beg; l0 < l0beg + 128; l0 += 32) {
    const u16* g = src + (size_t)((l0 + lr) * B_ + b) * E_ + h * 64 + ck;
    u16x8 d0 = *(const u16x8*)g;
    u16x8 d1 = *(const u16x8*)(g + 8);
    __syncthreads();                  // previous chunk fully consumed
    f32x4 f0, f1, f2, f3;
#pragma unroll
    for (int j = 0; j < 4; ++j) {
      f0[j] = bf2f(d0[j]); f1[j] = bf2f(d0[4 + j]);
      f2[j] = bf2f(d1[j]); f3[j] = bf2f(d1[4 + j]);
    }
    *(f32x4*)(dstrow) = f0; *(f32x4*)(dstrow + 4) = f1;
    *(f32x4*)(dstrow + 8) = f2; *(f32x4*)(dstrow + 12) = f3;
    __syncthreads();
#pragma unroll 8
    for (int p = 0; p < 32; ++p) {
      f32x4 kk = *(const f32x4*)&sK[p][td * 4];
      f32x4 vv = *(const f32x4*)&sV[p][te * 4];
#pragma unroll
      for (int i = 0; i < 4; ++i)
#pragma unroll
        for (int j = 0; j < 4; ++j)
          acc[i][j] = fmaf(kk[i], vv[j], acc[i][j]);
      if (tid < 64) srow += sK[p][tid];
      else if (tid < 128) srow += sV[p][tid - 64];
    }
  }
  float* Pp = Part + (size_t)(n * 16 + sy) * 4096;
#pragma unroll
  for (int j = 0; j < 4; ++j) {
    f32x4 v4 = {acc[0][j], acc[1][j], acc[2][j], acc[3][j]};
    *(f32x4*)(Pp + (te * 4 + j) * 64 + td * 4) = v4;
  }
  if (tid < 64) KPart[(n * 16 + sy) * 64 + tid] = srow;
  else if (tid < 128) VPart[(n * 16 + sy) * 64 + tid - 64] = srow;
}

// ---------- kv_reduce stage 2: sum 16 slice-partials ----------
// blocks [0,512): Mt (32*4096 outputs); [512,528): Ksum/Vsum (4096 outputs)
__global__ __launch_bounds__(256) void kv_merge(const float* __restrict__ Part,
    const float* __restrict__ KPart, const float* __restrict__ VPart,
    float* __restrict__ Mt, float* __restrict__ Ks, float* __restrict__ Vs) {
  const int bid = blockIdx.x, tid = threadIdx.x;
  if (bid < 512) {
    const int oi = bid * 256 + tid;            // 0..131071
    const int n = oi >> 12, j = oi & 4095;
    const float* p = Part + (size_t)n * 16 * 4096 + j;
    float s = 0.f;
#pragma unroll
    for (int sl = 0; sl < 16; ++sl) s += p[sl * 4096];
    Mt[oi] = s;
  } else {
    const int i = (bid - 512) * 256 + tid;     // 0..4095
    const int which = i >> 11, rem = i & 2047;
    const int n = rem >> 6, d = rem & 63;
    const float* p = (which ? VPart : KPart) + (n * 16) * 64 + d;
    float s = 0.f;
#pragma unroll
    for (int sl = 0; sl < 16; ++sl) s += p[sl * 64];
    if (which) Vs[n * 64 + d] = s; else Ks[n * 64 + d] = s;
  }
}

// ---------- apply: A = (2*Q@M + 62*Vsum) / den, den = 2*q.Ksum + 62*L ----------
// grid (NH, 16). Stages fp32 Mt -> bf16 sM in-kernel.
__global__ __launch_bounds__(256) void apply_mfma(const u16* __restrict__ Qbf,
    const float* __restrict__ Mt, const float* __restrict__ Ksum,
    const float* __restrict__ Vsum, u16* __restrict__ Abf) {
  __shared__ __align__(16) u16 sQ[128 * 64];
  __shared__ __align__(16) u16 sM[64 * 64];
  __shared__ float sKs[64], sVs[64], sDen[128];
  const int n = blockIdx.x, b = n >> 3, h = n & 7;
  const int l0 = blockIdx.y * 128;
  const int tid = threadIdx.x, w = tid >> 6, lane = tid & 63;
  const int fr = lane & 15, quad = lane >> 4;
#pragma unroll
  for (int j = 0; j < 4; ++j) {
    const int rloc = w * 32 + j * 8;
    const int row = rloc + (lane >> 3);
    const int k = (lane & 7) * 8;
    async16(Qbf + (size_t)((l0 + row) * B_ + b) * E_ + h * 64 + k, sQ + rloc * 64);
  }
  {  // Mt fp32 -> sM bf16
    const float* Mp = Mt + (size_t)n * 4096 + tid * 16;
    f32x4 m0 = *(const f32x4*)(Mp);
    f32x4 m1 = *(const f32x4*)(Mp + 4);
    f32x4 m2 = *(const f32x4*)(Mp + 8);
    f32x4 m3 = *(const f32x4*)(Mp + 12);
    u16x8 o0, o1;
#pragma unroll
    for (int j = 0; j < 4; ++j) {
      o0[j] = f2bf(m0[j]); o0[4 + j] = f2bf(m1[j]);
      o1[j] = f2bf(m2[j]); o1[4 + j] = f2bf(m3[j]);
    }
    *(u16x8*)(sM + tid * 16) = o0;
    *(u16x8*)(sM + tid * 16 + 8) = o1;
  }
  if (tid < 64) sKs[tid] = Ksum[n * 64 + tid];
  else if (tid < 128) sVs[tid - 64] = Vsum[n * 64 + tid - 64];
  __syncthreads();
  union { u16x8 u; bf16x8 bv; } aU[2][2];
  bf16x8 bF[4][2];
#pragma unroll
  for (int mt = 0; mt < 2; ++mt)
#pragma unroll
    for (int ks = 0; ks < 2; ++ks)
      aU[mt][ks].u = *(const u16x8*)(sQ + (w * 32 + mt * 16 + fr) * 64 + ks * 32 + quad * 8);
#pragma unroll
  for (int nt = 0; nt < 4; ++nt)
#pragma unroll
    for (int ks = 0; ks < 2; ++ks)
      bF[nt][ks] = *(const bf16x8*)(sM + (nt * 16 + fr) * 64 + ks * 32 + quad * 8);
  float pden[2] = {0.f, 0.f};
#pragma unroll
  for (int mt = 0; mt < 2; ++mt)
#pragma unroll
    for (int ks = 0; ks < 2; ++ks)
#pragma unroll
      for (int j = 0; j < 8; ++j)
        pden[mt] = fmaf(bf2f(aU[mt][ks].u[j]), sKs[ks * 32 + quad * 8 + j], pden[mt]);
#pragma unroll
  for (int mt = 0; mt < 2; ++mt) {
    pden[mt] += __shfl_xor(pden[mt], 16, 64);
    pden[mt] += __shfl_xor(pden[mt], 32, 64);
    if (quad == 0)
      sDen[w * 32 + mt * 16 + fr] = fmaxf(2.f * pden[mt] + 62.f * (float)L_, 1e-6f);
  }
  __syncthreads();
  f32x4 acc[2][4];
#pragma unroll
  for (int mt = 0; mt < 2; ++mt)
#pragma unroll
    for (int nt = 0; nt < 4; ++nt) {
      const float iv = 31.f * sVs[nt * 16 + fr];
      acc[mt][nt] = (f32x4){iv, iv, iv, iv};
#pragma unroll
      for (int ks = 0; ks < 2; ++ks)
        acc[mt][nt] = __builtin_amdgcn_mfma_f32_16x16x32_bf16(aU[mt][ks].bv, bF[nt][ks],
                                                              acc[mt][nt], 0, 0, 0);
    }
#pragma unroll
  for (int mt = 0; mt < 2; ++mt)
#pragma unroll
    for (int r = 0; r < 4; ++r) {
      const int rloc = w * 32 + mt * 16 + quad * 4 + r;
      const float invd = 2.f / sDen[rloc];
      const size_t orow = (size_t)((l0 + rloc) * B_ + b) * E_ + h * 64;
#pragma unroll
      for (int nt = 0; nt < 4; ++nt)
        Abf[orow + nt * 16 + fr] = f2bf(acc[mt][nt][r] * invd);
    }
}

extern "C" void kernel_launch(void* const* d_in, const int* in_sizes, int n_in,
                              void* d_out, int out_size, void* d_ws, size_t ws_size,
                              hipStream_t stream) {
  const float* query = (const float*)d_in[0];
  const float* Wq = (const float*)d_in[1];
  const float* bq = (const float*)d_in[2];
  const float* Wk = (const float*)d_in[3];
  const float* bk = (const float*)d_in[4];
  const float* Wv = (const float*)d_in[5];
  const float* bv = (const float*)d_in[6];
  const float* Wo = (const float*)d_in[7];
  const float* bo = (const float*)d_in[8];
  float* out = (float*)d_out;

  char* ws = (char*)d_ws;
  u16* Xbf  = (u16*)(ws);                        // 8 MB; dead after qkv_gemm
  u16* Qbf  = (u16*)(ws + 8388608);
  u16* Kbf  = (u16*)(ws + 16777216);
  u16* Vbf  = (u16*)(ws + 25165824);
  u16* Abf  = (u16*)(ws + 33554432);
  u16* Wqb  = (u16*)(ws + 41943040);             // 512 KB each
  u16* Wkb  = (u16*)(ws + 42467328);
  u16* Wvb  = (u16*)(ws + 42991616);
  u16* Wob  = (u16*)(ws + 43515904);
  float* Mt = (float*)(ws + 44040192);           // 512 KB (NH*4096 f32)
  float* Ks = (float*)(ws + 44564480);           // 8 KB
  float* Vs = (float*)(ws + 44572672);           // 8 KB
  float* KPart = (float*)(ws + 44580864);        // 128 KB (512*64 f32)
  float* VPart = (float*)(ws + 44711936);        // 128 KB
  float* Part  = (float*)Xbf;                    // alias: 512*4096 f32 = 8 MB exactly

  cvt_all<<<2560, 256, 0, stream>>>(query, Wq, Wk, Wv, Wo,
                                    Xbf, Wqb, Wkb, Wvb, Wob);
  qkv_gemm<<<dim3(NROW / 128, E_ / 64, 3), 256, 0, stream>>>(
      Xbf, Wqb, Wkb, Wvb, bq, bk, bv, Qbf, Kbf, Vbf);
  kv_part<<<dim3(NH, 16), 256, 0, stream>>>(Kbf, Vbf, Part, KPart, VPart);
  kv_merge<<<528, 256, 0, stream>>>(Part, KPart, VPart, Mt, Ks, Vs);
  apply_mfma<<<dim3(NH, L_ / 128), 256, 0, stream>>>(Qbf, Mt, Ks, Vs, Abf);
  gemm_out<<<dim3(NROW / 128, E_ / 64), 256, 0, stream>>>(Abf, Wob, bo, out);
}

// Round 9
// 141.952 us; speedup vs baseline: 1.1323x; 1.0258x over previous
//
#include <hip/hip_runtime.h>

#define B_ 4
#define L_ 2048
#define E_ 512
#define H_ 8
#define NROW (B_*L_)        // 8192 flat rows
#define SZ (NROW*E_)        // 4194304
#define NH (B_*H_)          // 32 batch-heads

typedef unsigned short u16;
typedef unsigned int u32;
typedef __attribute__((ext_vector_type(8))) __bf16 bf16x8;
typedef __attribute__((ext_vector_type(8))) u16 u16x8;
typedef __attribute__((ext_vector_type(4))) float f32x4;

__device__ __forceinline__ u16 f2bf(float f) {
  union { float f; u32 u; } v; v.f = f;
  u32 r = v.u + 0x7FFFu + ((v.u >> 16) & 1u);   // RNE
  return (u16)(r >> 16);
}
__device__ __forceinline__ float bf2f(u16 s) {
  union { u32 u; float f; } v; v.u = ((u32)s) << 16;
  return v.f;
}
// async global->LDS, 16B per lane. lds dest = wave-uniform base + lane*16.
__device__ __forceinline__ void async16(const u16* g, u16* l) {
  __builtin_amdgcn_global_load_lds(
      (const __attribute__((address_space(1))) u32*)g,
      (__attribute__((address_space(3))) u32*)l, 16, 0, 0);
}

// ---------- fused fp32->bf16 converts ----------
// blocks [0,2048): X ; [2048,2560): 4 weights (128 blocks each)
__global__ __launch_bounds__(256) void cvt_all(const float* __restrict__ X,
    const float* __restrict__ W0, const float* __restrict__ W1,
    const float* __restrict__ W2, const float* __restrict__ W3,
    u16* __restrict__ Y, u16* __restrict__ Y0, u16* __restrict__ Y1,
    u16* __restrict__ Y2, u16* __restrict__ Y3) {
  const int bid = blockIdx.x;
  const float* src;
  u16* dst;
  int off;
  if (bid < 2048) { src = X; dst = Y; off = bid * 2048; }
  else {
    const int t = bid - 2048, s = t >> 7, r = t & 127;
    src = (s == 0) ? W0 : (s == 1) ? W1 : (s == 2) ? W2 : W3;
    dst = (s == 0) ? Y0 : (s == 1) ? Y1 : (s == 2) ? Y2 : Y3;
    off = r * 2048;
  }
  const int i0 = off + threadIdx.x * 8;
  f32x4 a = *(const f32x4*)(src + i0);
  f32x4 b = *(const f32x4*)(src + i0 + 4);
  u16x8 o;
#pragma unroll
  for (int j = 0; j < 4; ++j) { o[j] = f2bf(a[j]); o[4 + j] = f2bf(b[j]); }
  *(u16x8*)(dst + i0) = o;
}

// ---------- QKV MFMA GEMM: m97 geometry. 128x128 tile, BK=64, grid (64,4,3) ----------
// 4 waves 2x2, each 64x64 -> 32 MFMA per barrier pair. 3 blocks/CU pinned.
// Wave cols bn+wn..+64 = exactly one head slice -> softmax stays wave-local.
// z=0: Q (+softmax64), z=1: K (+softmax64), z=2: V (plain bf16)
__global__ __launch_bounds__(256, 3) void qkv_gemm(const u16* __restrict__ X,
    const u16* __restrict__ Wq, const u16* __restrict__ Wk, const u16* __restrict__ Wv,
    const float* __restrict__ bq, const float* __restrict__ bk, const float* __restrict__ bv,
    u16* __restrict__ Qo, u16* __restrict__ Ko, u16* __restrict__ Vo) {
  __shared__ __align__(16) union {
    struct { u16 a[2][128 * 32]; u16 b[2][128 * 32]; } st;  // 32 KB staging
    u16 ep[4][16 * 72];                                     // per-wave epilogue stage
  } sh;
  const int z = blockIdx.z;
  const u16* W = (z == 0) ? Wq : (z == 1) ? Wk : Wv;
  const float* bias = (z == 0) ? bq : (z == 1) ? bk : bv;
  u16* C = (z == 0) ? Qo : (z == 1) ? Ko : Vo;
  const int tid = threadIdx.x;
  const int w = tid >> 6, lane = tid & 63;
  const int bm = blockIdx.x * 128, bn = blockIdx.y * 128;
  const int wm = (w >> 1) * 64, wn = (w & 1) * 64;
  const int fr = lane & 15, quad = lane >> 4;
  const int c0 = tid, c1 = tid + 256;      // chunk ids within a 128x32 panel
  const int ar0 = c0 >> 2, ak0 = (c0 & 3) * 8;
  const int ar1 = c1 >> 2, ak1 = (c1 & 3) * 8;
  f32x4 acc[4][4] = {};
  for (int k0 = 0; k0 < E_; k0 += 64) {
    __syncthreads();
#pragma unroll
    for (int p = 0; p < 2; ++p) {
      const int kp = k0 + p * 32;
      async16(X + (size_t)(bm + ar0) * E_ + kp + ak0, sh.st.a[p] + c0 * 8);
      async16(X + (size_t)(bm + ar1) * E_ + kp + ak1, sh.st.a[p] + c1 * 8);
      async16(W + (size_t)(bn + ar0) * E_ + kp + ak0, sh.st.b[p] + c0 * 8);
      async16(W + (size_t)(bn + ar1) * E_ + kp + ak1, sh.st.b[p] + c1 * 8);
    }
    __syncthreads();
#pragma unroll
    for (int p = 0; p < 2; ++p) {
      bf16x8 af[4], bf[4];
#pragma unroll
      for (int t = 0; t < 4; ++t) {
        af[t] = *(const bf16x8*)(sh.st.a[p] + (wm + t * 16 + fr) * 32 + quad * 8);
        bf[t] = *(const bf16x8*)(sh.st.b[p] + (wn + t * 16 + fr) * 32 + quad * 8);
      }
#pragma unroll
      for (int i = 0; i < 4; ++i)
#pragma unroll
        for (int j = 0; j < 4; ++j)
          acc[i][j] = __builtin_amdgcn_mfma_f32_16x16x32_bf16(af[i], bf[j], acc[i][j], 0, 0, 0);
    }
  }
  __syncthreads();   // all fragment reads done before LDS reuse
  u16* ep = sh.ep[w];
#pragma unroll
  for (int i = 0; i < 4; ++i) {   // 16-row slab of the wave's 64x64 tile
    if (z < 2) {
#pragma unroll
      for (int r = 0; r < 4; ++r) {
        float v[4];
#pragma unroll
        for (int nt = 0; nt < 4; ++nt)
          v[nt] = acc[i][nt][r] + bias[bn + wn + nt * 16 + fr];
        float mx = fmaxf(fmaxf(v[0], v[1]), fmaxf(v[2], v[3]));
#pragma unroll
        for (int off = 1; off < 16; off <<= 1) mx = fmaxf(mx, __shfl_xor(mx, off, 64));
        float e[4], ssum = 0.f;
#pragma unroll
        for (int nt = 0; nt < 4; ++nt) { e[nt] = __expf(v[nt] - mx); ssum += e[nt]; }
#pragma unroll
        for (int off = 1; off < 16; off <<= 1) ssum += __shfl_xor(ssum, off, 64);
        const float inv = 1.f / ssum;
#pragma unroll
        for (int nt = 0; nt < 4; ++nt)
          ep[(quad * 4 + r) * 72 + nt * 16 + fr] = f2bf(e[nt] * inv);
      }
    } else {
#pragma unroll
      for (int r = 0; r < 4; ++r)
#pragma unroll
        for (int nt = 0; nt < 4; ++nt)
          ep[(quad * 4 + r) * 72 + nt * 16 + fr] =
              f2bf(acc[i][nt][r] + bias[bn + wn + nt * 16 + fr]);
    }
    // coalesced store: 16 rows x 64 cols bf16
#pragma unroll
    for (int pass = 0; pass < 2; ++pass) {
      const int row = pass * 8 + (lane >> 3), ch = lane & 7;
      u16x8 val = *(const u16x8*)(ep + row * 72 + ch * 8);
      *(u16x8*)(C + (size_t)(bm + wm + i * 16 + row) * E_ + bn + wn + ch * 8) = val;
    }
  }
}

// ---------- out-projection GEMM: 128x64 tile, two BK=32 panels, fp32 out, grid (64,8) ----------
__global__ __launch_bounds__(256) void gemm_out(const u16* __restrict__ X,
    const u16* __restrict__ W, const float* __restrict__ bias, float* __restrict__ C) {
  __shared__ __align__(16) union {
    struct { u16 a[2][128 * 32]; u16 b[2][64 * 32]; } st;  // 24 KB
    float ep[4][16 * 68];                                  // per-wave fp32 stage
  } sh;
  const int tid = threadIdx.x;
  const int w = tid >> 6, lane = tid & 63;
  const int bm = blockIdx.x * 128, bn = blockIdx.y * 64;
  const int fr = lane & 15, quad = lane >> 4;
  const int c0 = tid, c1 = tid + 256;
  const int ar0 = c0 >> 2, ak0 = (c0 & 3) * 8;
  const int ar1 = c1 >> 2, ak1 = (c1 & 3) * 8;
  f32x4 acc[2][4] = {};
  for (int k0 = 0; k0 < E_; k0 += 64) {
    __syncthreads();
#pragma unroll
    for (int p = 0; p < 2; ++p) {
      const int kp = k0 + p * 32;
      async16(X + (size_t)(bm + ar0) * E_ + kp + ak0, sh.st.a[p] + c0 * 8);
      async16(X + (size_t)(bm + ar1) * E_ + kp + ak1, sh.st.a[p] + c1 * 8);
      async16(W + (size_t)(bn + ar0) * E_ + kp + ak0, sh.st.b[p] + c0 * 8);
    }
    __syncthreads();
#pragma unroll
    for (int p = 0; p < 2; ++p) {
      bf16x8 af[2], bf[4];
#pragma unroll
      for (int mt = 0; mt < 2; ++mt)
        af[mt] = *(const bf16x8*)(sh.st.a[p] + (w * 32 + mt * 16 + fr) * 32 + quad * 8);
#pragma unroll
      for (int nt = 0; nt < 4; ++nt)
        bf[nt] = *(const bf16x8*)(sh.st.b[p] + (nt * 16 + fr) * 32 + quad * 8);
#pragma unroll
      for (int mt = 0; mt < 2; ++mt)
#pragma unroll
        for (int nt = 0; nt < 4; ++nt)
          acc[mt][nt] = __builtin_amdgcn_mfma_f32_16x16x32_bf16(af[mt], bf[nt],
                                                                acc[mt][nt], 0, 0, 0);
    }
  }
  __syncthreads();
  float* ep = sh.ep[w];
#pragma unroll
  for (int mt = 0; mt < 2; ++mt) {
#pragma unroll
    for (int r = 0; r < 4; ++r)
#pragma unroll
      for (int nt = 0; nt < 4; ++nt)
        ep[(quad * 4 + r) * 68 + nt * 16 + fr] = acc[mt][nt][r] + bias[bn + nt * 16 + fr];
#pragma unroll
    for (int p = 0; p < 4; ++p) {
      const int id = p * 64 + lane;
      const int row = id >> 4, ch = id & 15;
      f32x4 val = *(const f32x4*)(ep + row * 68 + ch * 4);
      *(f32x4*)(C + (size_t)(bm + w * 32 + mt * 16 + row) * E_ + bn + ch * 4) = val;
    }
  }
}

// ---------- kv_reduce stage 1: grid (NH, 16), 128 rows/block, NO atomics ----------
// Part[(n*16+sy)*4096 + e*64 + d] = partial sum_l K[l][d]*V[l][e]  (Mt layout [e][d])
__global__ __launch_bounds__(256) void kv_part(const u16* __restrict__ K,
    const u16* __restrict__ V, float* __restrict__ Part,
    float* __restrict__ KPart, float* __restrict__ VPart) {
  const int n = blockIdx.x, b = n >> 3, h = n & 7;
  const int sy = blockIdx.y;
  const int tid = threadIdx.x;
  const int td = tid & 15, te = tid >> 4;
  __shared__ float sK[32][68], sV[32][68];   // +4 pad
  float acc[4][4] = {};
  float srow = 0.f;
  const int which = tid >> 7, sub = tid & 127;       // 128 threads per tensor
  const int lr = sub >> 2, ck = (sub & 3) * 16;      // row 0..31, col {0,16,32,48}
  const u16* src = which ? V : K;
  float* dstrow = which ? &sV[lr][ck] : &sK[lr][ck];
  const int l0beg = sy * 128;
  for (int l0 = l0beg; l0 < l0beg + 128; l0 += 32) {
    const u16* g = src + (size_t)((l0 + lr) * B_ + b) * E_ + h * 64 + ck;
    u16x8 d0 = *(const u16x8*)g;
    u16x8 d1 = *(const u16x8*)(g + 8);
    __syncthreads();                  // previous chunk fully consumed
    f32x4 f0, f1, f2, f3;
#pragma unroll
    for (int j = 0; j < 4; ++j) {
      f0[j] = bf2f(d0[j]); f1[j] = bf2f(d0[4 + j]);
      f2[j] = bf2f(d1[j]); f3[j] = bf2f(d1[4 + j]);
    }
    *(f32x4*)(dstrow) = f0; *(f32x4*)(dstrow + 4) = f1;
    *(f32x4*)(dstrow + 8) = f2; *(f32x4*)(dstrow + 12) = f3;
    __syncthreads();
#pragma unroll 8
    for (int p = 0; p < 32; ++p) {
      f32x4 kk = *(const f32x4*)&sK[p][td * 4];
      f32x4 vv = *(const f32x4*)&sV[p][te * 4];
#pragma unroll
      for (int i = 0; i < 4; ++i)
#pragma unroll
        for (int j = 0; j < 4; ++j)
          acc[i][j] = fmaf(kk[i], vv[j], acc[i][j]);
      if (tid < 64) srow += sK[p][tid];
      else if (tid < 128) srow += sV[p][tid - 64];
    }
  }
  float* Pp = Part + (size_t)(n * 16 + sy) * 4096;
#pragma unroll
  for (int j = 0; j < 4; ++j) {
    f32x4 v4 = {acc[0][j], acc[1][j], acc[2][j], acc[3][j]};
    *(f32x4*)(Pp + (te * 4 + j) * 64 + td * 4) = v4;
  }
  if (tid < 64) KPart[(n * 16 + sy) * 64 + tid] = srow;
  else if (tid < 128) VPart[(n * 16 + sy) * 64 + tid - 64] = srow;
}

// ---------- kv_reduce stage 2: sum 16 slice-partials; Mt emitted as bf16 ----------
// blocks [0,512): Mtbf (32*4096 outputs); [512,528): Ksum/Vsum (4096 outputs)
__global__ __launch_bounds__(256) void kv_merge(const float* __restrict__ Part,
    const float* __restrict__ KPart, const float* __restrict__ VPart,
    u16* __restrict__ Mtbf, float* __restrict__ Ks, float* __restrict__ Vs) {
  const int bid = blockIdx.x, tid = threadIdx.x;
  if (bid < 512) {
    const int oi = bid * 256 + tid;            // 0..131071
    const int n = oi >> 12, j = oi & 4095;
    const float* p = Part + (size_t)n * 16 * 4096 + j;
    float s = 0.f;
#pragma unroll
    for (int sl = 0; sl < 16; ++sl) s += p[sl * 4096];
    Mtbf[oi] = f2bf(s);
  } else {
    const int i = (bid - 512) * 256 + tid;     // 0..4095
    const int which = i >> 11, rem = i & 2047;
    const int n = rem >> 6, d = rem & 63;
    const float* p = (which ? VPart : KPart) + (n * 16) * 64 + d;
    float s = 0.f;
#pragma unroll
    for (int sl = 0; sl < 16; ++sl) s += p[sl * 64];
    if (which) Vs[n * 64 + d] = s; else Ks[n * 64 + d] = s;
  }
}

// ---------- apply: A = (2*Q@M + 62*Vsum) / den, den = 2*q.Ksum + 62*L ----------
// grid (NH, 16). sM async-loaded directly from bf16 Mtbf.
__global__ __launch_bounds__(256) void apply_mfma(const u16* __restrict__ Qbf,
    const u16* __restrict__ Mtbf, const float* __restrict__ Ksum,
    const float* __restrict__ Vsum, u16* __restrict__ Abf) {
  __shared__ __align__(16) u16 sQ[128 * 64];
  __shared__ __align__(16) u16 sM[64 * 64];
  __shared__ float sKs[64], sVs[64], sDen[128];
  const int n = blockIdx.x, b = n >> 3, h = n & 7;
  const int l0 = blockIdx.y * 128;
  const int tid = threadIdx.x, w = tid >> 6, lane = tid & 63;
  const int fr = lane & 15, quad = lane >> 4;
#pragma unroll
  for (int j = 0; j < 4; ++j) {
    const int rloc = w * 32 + j * 8;
    const int row = rloc + (lane >> 3);
    const int k = (lane & 7) * 8;
    async16(Qbf + (size_t)((l0 + row) * B_ + b) * E_ + h * 64 + k, sQ + rloc * 64);
  }
#pragma unroll
  for (int j = 0; j < 2; ++j) {
    const int c = j * 256 + tid;               // 512 chunks of 8 bf16
    async16(Mtbf + (size_t)n * 4096 + c * 8, sM + c * 8);
  }
  if (tid < 64) sKs[tid] = Ksum[n * 64 + tid];
  else if (tid < 128) sVs[tid - 64] = Vsum[n * 64 + tid - 64];
  __syncthreads();
  union { u16x8 u; bf16x8 bv; } aU[2][2];
  bf16x8 bF[4][2];
#pragma unroll
  for (int mt = 0; mt < 2; ++mt)
#pragma unroll
    for (int ks = 0; ks < 2; ++ks)
      aU[mt][ks].u = *(const u16x8*)(sQ + (w * 32 + mt * 16 + fr) * 64 + ks * 32 + quad * 8);
#pragma unroll
  for (int nt = 0; nt < 4; ++nt)
#pragma unroll
    for (int ks = 0; ks < 2; ++ks)
      bF[nt][ks] = *(const bf16x8*)(sM + (nt * 16 + fr) * 64 + ks * 32 + quad * 8);
  float pden[2] = {0.f, 0.f};
#pragma unroll
  for (int mt = 0; mt < 2; ++mt)
#pragma unroll
    for (int ks = 0; ks < 2; ++ks)
#pragma unroll
      for (int j = 0; j < 8; ++j)
        pden[mt] = fmaf(bf2f(aU[mt][ks].u[j]), sKs[ks * 32 + quad * 8 + j], pden[mt]);
#pragma unroll
  for (int mt = 0; mt < 2; ++mt) {
    pden[mt] += __shfl_xor(pden[mt], 16, 64);
    pden[mt] += __shfl_xor(pden[mt], 32, 64);
    if (quad == 0)
      sDen[w * 32 + mt * 16 + fr] = fmaxf(2.f * pden[mt] + 62.f * (float)L_, 1e-6f);
  }
  __syncthreads();
  f32x4 acc[2][4];
#pragma unroll
  for (int mt = 0; mt < 2; ++mt)
#pragma unroll
    for (int nt = 0; nt < 4; ++nt) {
      const float iv = 31.f * sVs[nt * 16 + fr];
      acc[mt][nt] = (f32x4){iv, iv, iv, iv};
#pragma unroll
      for (int ks = 0; ks < 2; ++ks)
        acc[mt][nt] = __builtin_amdgcn_mfma_f32_16x16x32_bf16(aU[mt][ks].bv, bF[nt][ks],
                                                              acc[mt][nt], 0, 0, 0);
    }
#pragma unroll
  for (int mt = 0; mt < 2; ++mt)
#pragma unroll
    for (int r = 0; r < 4; ++r) {
      const int rloc = w * 32 + mt * 16 + quad * 4 + r;
      const float invd = 2.f / sDen[rloc];
      const size_t orow = (size_t)((l0 + rloc) * B_ + b) * E_ + h * 64;
#pragma unroll
      for (int nt = 0; nt < 4; ++nt)
        Abf[orow + nt * 16 + fr] = f2bf(acc[mt][nt][r] * invd);
    }
}

extern "C" void kernel_launch(void* const* d_in, const int* in_sizes, int n_in,
                              void* d_out, int out_size, void* d_ws, size_t ws_size,
                              hipStream_t stream) {
  const float* query = (const float*)d_in[0];
  const float* Wq = (const float*)d_in[1];
  const float* bq = (const float*)d_in[2];
  const float* Wk = (const float*)d_in[3];
  const float* bk = (const float*)d_in[4];
  const float* Wv = (const float*)d_in[5];
  const float* bv = (const float*)d_in[6];
  const float* Wo = (const float*)d_in[7];
  const float* bo = (const float*)d_in[8];
  float* out = (float*)d_out;

  char* ws = (char*)d_ws;
  u16* Xbf  = (u16*)(ws);                        // 8 MB; dead after qkv_gemm
  u16* Qbf  = (u16*)(ws + 8388608);
  u16* Kbf  = (u16*)(ws + 16777216);
  u16* Vbf  = (u16*)(ws + 25165824);
  u16* Abf  = (u16*)(ws + 33554432);
  u16* Wqb  = (u16*)(ws + 41943040);             // 512 KB each
  u16* Wkb  = (u16*)(ws + 42467328);
  u16* Wvb  = (u16*)(ws + 42991616);
  u16* Wob  = (u16*)(ws + 43515904);
  u16* Mtbf = (u16*)(ws + 44040192);             // 256 KB (NH*4096 bf16)
  float* Ks = (float*)(ws + 44564480);           // 8 KB
  float* Vs = (float*)(ws + 44572672);           // 8 KB
  float* KPart = (float*)(ws + 44580864);        // 128 KB (512*64 f32)
  float* VPart = (float*)(ws + 44711936);        // 128 KB
  float* Part  = (float*)Xbf;                    // alias: 512*4096 f32 = 8 MB exactly

  cvt_all<<<2560, 256, 0, stream>>>(query, Wq, Wk, Wv, Wo,
                                    Xbf, Wqb, Wkb, Wvb, Wob);
  qkv_gemm<<<dim3(NROW / 128, E_ / 128, 3), 256, 0, stream>>>(
      Xbf, Wqb, Wkb, Wvb, bq, bk, bv, Qbf, Kbf, Vbf);
  kv_part<<<dim3(NH, 16), 256, 0, stream>>>(Kbf, Vbf, Part, KPart, VPart);
  kv_merge<<<528, 256, 0, stream>>>(Part, KPart, VPart, Mtbf, Ks, Vs);
  apply_mfma<<<dim3(NH, L_ / 128), 256, 0, stream>>>(Qbf, Mtbf, Ks, Vs, Abf);
  gemm_out<<<dim3(NROW / 128, E_ / 64), 256, 0, stream>>>(Abf, Wob, bo, out);
}